// Round 6
// baseline (1263.570 us; speedup 1.0000x reference)
//
#include <hip/hip_runtime.h>
#include <hip/hip_bf16.h>
#include <hip/hip_fp16.h>
#include <math.h>

// Shapes: x [128,20000,1] f32; rows/cols [640000] i32; vals [640000] f32
// W_gc [20,10]; b_gc [10]; W_fc [200000,10]; b_fc [10]; out [128,10] f32.
//
// R19: L2-resident SpMM. Theory: the 25us/step floor = L2 THRASH (per-XCD
// working set 5.12MB > 4MB L2 -> every random gather misses to LLC at
// 6.5TB/s: 164MB/step = 25.2us, exactly measured).
//  - BCG=16, 8 chunks, ONE CHUNK PER XCD (blk&7). Per-XCD plane region
//    640KB -> gathers hit local L2 (~34TB/s aggregate) after a 5MB fill.
//  - Plane-major layout X16[c][k][n][16]: each k-plane a contiguous 640KB
//    region (no mixed-k lines -> no stale-L1 hazard, clean residency).
//  - csr packed 4B/edge (col<<16 | fp16(val)) since each XCD reads the
//    full edge list; csr + carry accessed NONTEMPORAL (don't pollute L2).
//  - Chunk recursion is XCD-independent: no cross-XCD motion after step 1.
//  - proj_fc: R17 scalar-weight structure, re-indexed (wave = node,
//    lanes = 4 chunks x 16 bb, 2 waves/node).

#define NF 10
#define KCHEB 20
#define BCG 16                        // batch elems per chunk
#define NCH 8                         // chunks (one per XCD)

typedef unsigned int u32;
typedef float v4f __attribute__((ext_vector_type(4)));

// ---------------- CSR build + small prep ----------------

__global__ void init_kernel(int* counts, float* h_part, const float* __restrict__ W_gc,
                            float* __restrict__ WgT, int N, int H) {
    int i = blockIdx.x * blockDim.x + threadIdx.x;
    if (i < N) counts[i] = 0;
    if (i < H) h_part[i] = 0.f;
    if (i < KCHEB * NF) WgT[(i % NF) * KCHEB + (i / NF)] = W_gc[i];  // [j][k]
}

__global__ void hist_kernel(const int* __restrict__ rows, int* __restrict__ counts, int E) {
    int e = blockIdx.x * blockDim.x + threadIdx.x;
    if (e < E) atomicAdd(&counts[rows[e]], 1);
}

#define SCAN_THREADS 1024
__global__ void scan_kernel(const int* __restrict__ counts, int* __restrict__ row_start,
                            int* __restrict__ cursor, int N) {
    __shared__ int sh[SCAN_THREADS];
    int t = threadIdx.x;
    int CH = (N + SCAN_THREADS - 1) / SCAN_THREADS;
    int base = t * CH;
    int sum = 0;
    for (int i = 0; i < CH; ++i) {
        int idx = base + i;
        sum += (idx < N) ? counts[idx] : 0;
    }
    sh[t] = sum;
    __syncthreads();
    for (int off = 1; off < SCAN_THREADS; off <<= 1) {
        int v = (t >= off) ? sh[t - off] : 0;
        __syncthreads();
        sh[t] += v;
        __syncthreads();
    }
    int run = (t == 0) ? 0 : sh[t - 1];
    for (int i = 0; i < CH; ++i) {
        int idx = base + i;
        if (idx < N) {
            int v = counts[idx];
            row_start[idx] = run;
            cursor[idx] = run;
            run += v;
        }
    }
    if (t == SCAN_THREADS - 1) row_start[N] = run;
}

// csr[p] = (col << 16) | fp16bits(val)   (N=20000 < 65536)
__global__ void scatter_kernel(const int* __restrict__ rows, const int* __restrict__ cols,
                               const float* __restrict__ vals, int* __restrict__ cursor,
                               u32* __restrict__ csr, int E) {
    int e = blockIdx.x * blockDim.x + threadIdx.x;
    if (e >= E) return;
    int p = atomicAdd(&cursor[rows[e]], 1);
    __half hv = __float2half_rn(vals[e]);
    csr[p] = ((u32)cols[e] << 16) | (u32)__half_as_ushort(hv);
}

// ---------------- T0 fill (tiled transpose; plane-major k=0 + carry 0) ----

__global__ void transpose_kernel(const float* __restrict__ x, __half* __restrict__ X16,
                                 float* __restrict__ C32, int N, int b0s) {
    __shared__ float tile[128][65];
    int tid = threadIdx.x;
    int n0 = blockIdx.x * 64;
#pragma unroll
    for (int p = 0; p < 32; ++p) {
        int idx = p * 256 + tid;
        int bl = idx >> 6;         // batch 0..127
        int nl = idx & 63;
        if (n0 + nl < N)
            tile[bl][nl] = x[(size_t)(b0s + bl) * N + n0 + nl];
    }
    __syncthreads();
    // plane k=0: 8 chunks x 64 n x 2 halves
#pragma unroll
    for (int p = 0; p < 4; ++p) {
        int idx = p * 256 + tid;
        int cc = idx >> 7;
        int nl = (idx >> 1) & 63;
        int hf = idx & 1;
        int n = n0 + nl;
        if (n < N) {
            __half hbuf[8];
#pragma unroll
            for (int q = 0; q < 8; ++q)
                hbuf[q] = __float2half_rn(tile[cc * 16 + hf * 8 + q][nl]);
            *(uint4*)(X16 + ((size_t)cc * KCHEB + 0) * N * 16 + (size_t)n * 16 + hf * 8) =
                *(uint4*)hbuf;
        }
    }
    // carry slot 0: 8 chunks x 64 n x 4 quads
#pragma unroll
    for (int p = 0; p < 8; ++p) {
        int idx = p * 256 + tid;
        int cc = idx >> 8;
        int rem = idx & 255;
        int nl = rem >> 2;
        int qd = rem & 3;
        int n = n0 + nl;
        if (n < N) {
            float4 f4 = make_float4(tile[cc * 16 + qd * 4 + 0][nl],
                                    tile[cc * 16 + qd * 4 + 1][nl],
                                    tile[cc * 16 + qd * 4 + 2][nl],
                                    tile[cc * 16 + qd * 4 + 3][nl]);
            *(float4*)(C32 + ((size_t)cc * 2 + 0) * N * 16 + (size_t)n * 16 + qd * 4) = f4;
        }
    }
}

// ---------------- SpMM step (per-XCD chunk, L2-resident) ----------------
// Block = 256 thr = 128 rows x 2 half-lanes; chunk = blockIdx&7 = XCD.
// Per edge: 16 fp16 = 32B gather from the chunk's 640KB plane region.
// csr + carry nontemporal (bypass/no-pollute L2); plane read/write normal.

__global__ __launch_bounds__(256)
void spmm_kernel(__half* __restrict__ X16, float* __restrict__ C32,
                 const int* __restrict__ row_start, const u32* __restrict__ csr,
                 int N, int kIn, int kOut, float alpha, float beta) {
    int c = blockIdx.x & 7;
    int sub = blockIdx.x >> 3;
    int tid = threadIdx.x;
    int ln = tid >> 1;             // row 0..127
    int hf = tid & 1;
    int n = sub * 128 + ln;
    if (n >= N) return;
    int s = row_start[n];
    int e = row_start[n + 1];

    const __half* gin = X16 + ((size_t)c * KCHEB + kIn) * N * 16;
    int bo = hf * 8;
    float acc[8];
#pragma unroll
    for (int q = 0; q < 8; ++q) acc[q] = 0.f;

    int i = s;
    for (; i + 4 <= e; i += 4) {
        u32 pv0 = __builtin_nontemporal_load(csr + i);
        u32 pv1 = __builtin_nontemporal_load(csr + i + 1);
        u32 pv2 = __builtin_nontemporal_load(csr + i + 2);
        u32 pv3 = __builtin_nontemporal_load(csr + i + 3);
        uint4 u0 = *(const uint4*)(gin + (size_t)(pv0 >> 16) * 16 + bo);
        uint4 u1 = *(const uint4*)(gin + (size_t)(pv1 >> 16) * 16 + bo);
        uint4 u2 = *(const uint4*)(gin + (size_t)(pv2 >> 16) * 16 + bo);
        uint4 u3 = *(const uint4*)(gin + (size_t)(pv3 >> 16) * 16 + bo);
        float v0 = __half2float(__ushort_as_half((unsigned short)(pv0 & 0xffffu)));
        float v1 = __half2float(__ushort_as_half((unsigned short)(pv1 & 0xffffu)));
        float v2 = __half2float(__ushort_as_half((unsigned short)(pv2 & 0xffffu)));
        float v3 = __half2float(__ushort_as_half((unsigned short)(pv3 & 0xffffu)));
        {
            float2 f0 = __half22float2(*(__half2*)&u0.x), f1 = __half22float2(*(__half2*)&u0.y);
            float2 f2 = __half22float2(*(__half2*)&u0.z), f3 = __half22float2(*(__half2*)&u0.w);
            acc[0] += v0 * f0.x; acc[1] += v0 * f0.y; acc[2] += v0 * f1.x; acc[3] += v0 * f1.y;
            acc[4] += v0 * f2.x; acc[5] += v0 * f2.y; acc[6] += v0 * f3.x; acc[7] += v0 * f3.y;
        }
        {
            float2 f0 = __half22float2(*(__half2*)&u1.x), f1 = __half22float2(*(__half2*)&u1.y);
            float2 f2 = __half22float2(*(__half2*)&u1.z), f3 = __half22float2(*(__half2*)&u1.w);
            acc[0] += v1 * f0.x; acc[1] += v1 * f0.y; acc[2] += v1 * f1.x; acc[3] += v1 * f1.y;
            acc[4] += v1 * f2.x; acc[5] += v1 * f2.y; acc[6] += v1 * f3.x; acc[7] += v1 * f3.y;
        }
        {
            float2 f0 = __half22float2(*(__half2*)&u2.x), f1 = __half22float2(*(__half2*)&u2.y);
            float2 f2 = __half22float2(*(__half2*)&u2.z), f3 = __half22float2(*(__half2*)&u2.w);
            acc[0] += v2 * f0.x; acc[1] += v2 * f0.y; acc[2] += v2 * f1.x; acc[3] += v2 * f1.y;
            acc[4] += v2 * f2.x; acc[5] += v2 * f2.y; acc[6] += v2 * f3.x; acc[7] += v2 * f3.y;
        }
        {
            float2 f0 = __half22float2(*(__half2*)&u3.x), f1 = __half22float2(*(__half2*)&u3.y);
            float2 f2 = __half22float2(*(__half2*)&u3.z), f3 = __half22float2(*(__half2*)&u3.w);
            acc[0] += v3 * f0.x; acc[1] += v3 * f0.y; acc[2] += v3 * f1.x; acc[3] += v3 * f1.y;
            acc[4] += v3 * f2.x; acc[5] += v3 * f2.y; acc[6] += v3 * f3.x; acc[7] += v3 * f3.y;
        }
    }
    for (; i < e; ++i) {
        u32 pv0 = __builtin_nontemporal_load(csr + i);
        uint4 u0 = *(const uint4*)(gin + (size_t)(pv0 >> 16) * 16 + bo);
        float v0 = __half2float(__ushort_as_half((unsigned short)(pv0 & 0xffffu)));
        float2 f0 = __half22float2(*(__half2*)&u0.x), f1 = __half22float2(*(__half2*)&u0.y);
        float2 f2 = __half22float2(*(__half2*)&u0.z), f3 = __half22float2(*(__half2*)&u0.w);
        acc[0] += v0 * f0.x; acc[1] += v0 * f0.y; acc[2] += v0 * f1.x; acc[3] += v0 * f1.y;
        acc[4] += v0 * f2.x; acc[5] += v0 * f2.y; acc[6] += v0 * f3.x; acc[7] += v0 * f3.y;
    }

    // carry slot: (k-2)&1 == k&1 -> RMW same address (thread-private, safe)
    float* cs = C32 + (((size_t)c * 2 + (kOut & 1)) * N + n) * 16 + bo;
    float o[8];
#pragma unroll
    for (int q = 0; q < 8; ++q) o[q] = alpha * acc[q];
    if (beta != 0.f) {
        v4f pv0 = __builtin_nontemporal_load((const v4f*)cs);
        v4f pv1 = __builtin_nontemporal_load((const v4f*)(cs + 4));
        o[0] += beta * pv0.x; o[1] += beta * pv0.y; o[2] += beta * pv0.z; o[3] += beta * pv0.w;
        o[4] += beta * pv1.x; o[5] += beta * pv1.y; o[6] += beta * pv1.z; o[7] += beta * pv1.w;
    }
    v4f s0 = { o[0], o[1], o[2], o[3] };
    v4f s1 = { o[4], o[5], o[6], o[7] };
    __builtin_nontemporal_store(s0, (v4f*)cs);
    __builtin_nontemporal_store(s1, (v4f*)(cs + 4));
    __half* oo = X16 + ((size_t)c * KCHEB + kOut) * N * 16 + (size_t)n * 16 + bo;
    uint4 h4;
    __half2 h01 = __floats2half2_rn(o[0], o[1]);
    __half2 h23 = __floats2half2_rn(o[2], o[3]);
    __half2 h45 = __floats2half2_rn(o[4], o[5]);
    __half2 h67 = __floats2half2_rn(o[6], o[7]);
    h4.x = *(u32*)&h01; h4.y = *(u32*)&h23; h4.z = *(u32*)&h45; h4.w = *(u32*)&h67;
    *(uint4*)oo = h4;                      // normal store: keep L2-resident
}

// ---------------- Fused projection + FC partial ----------------
// 1024 thr = 16 waves. Wave = one node; lanes = 4 chunks x 16 bb; two waves
// (g0=0/4) cover all 128 batch. Weights wave-uniform -> scalar loads.

__global__ __launch_bounds__(1024, 8)
void proj_fc_kernel(const __half* __restrict__ X16,
                    const float* __restrict__ WgT,    // [j][k] = [10][20]
                    const float* __restrict__ b_gc,
                    const float* __restrict__ W_fc,
                    float* __restrict__ h_part,
                    int N, int b0s) {
    __shared__ float sRed[128 * 11];
    int tid = threadIdx.x;
    for (int i = tid; i < 128 * 11; i += 1024) sRed[i] = 0.f;
    __syncthreads();

    int lane = tid & 63;
    int bb = lane & 15;
    int lg = lane >> 4;                                  // 0..3
    int wv = __builtin_amdgcn_readfirstlane(tid >> 6);   // wave 0..15, uniform
    int nslot = wv >> 1;                                 // 0..7
    int g0 = (wv & 1) * 4;
    int g = g0 + lg;                                     // chunk 0..7
    int b = g * 16 + bb;                                 // batch 0..127

    float h_loc[NF];
#pragma unroll
    for (int f = 0; f < NF; ++f) h_loc[f] = 0.f;

    int ngroups = (N + 7) / 8;
    for (int grp = blockIdx.x; grp < ngroups; grp += gridDim.x) {
        int n = grp * 8 + nslot;                         // uniform per wave
        if (n < N) {
            float xt[KCHEB];
#pragma unroll
            for (int k = 0; k < KCHEB; ++k)
                xt[k] = __half2float(X16[((size_t)g * KCHEB + k) * N * 16 + (size_t)n * 16 + bb]);

            const float* wfBase = W_fc + (size_t)n * (NF * NF);
#pragma unroll 1
            for (int j = 0; j < NF; ++j) {
                const float* wg = WgT + j * KCHEB;
                float gc = b_gc[j];
#pragma unroll
                for (int k = 0; k < KCHEB; ++k) gc += wg[k] * xt[k];
                gc = fmaxf(gc, 0.f);
                const float* wf = wfBase + j * NF;
#pragma unroll
                for (int f = 0; f < NF; ++f) h_loc[f] += gc * wf[f];
            }
        }
    }
#pragma unroll
    for (int f = 0; f < NF; ++f) atomicAdd(&sRed[b * 11 + f], h_loc[f]);
    __syncthreads();
    for (int i = tid; i < 128 * NF; i += 1024) {
        int rb = i / NF;
        int rf = i - rb * NF;
        atomicAdd(&h_part[(size_t)(b0s + rb) * NF + rf], sRed[rb * 11 + rf]);
    }
}

// ---------------- Bias + ReLU + softmax ----------------

__global__ void softmax_kernel(const float* __restrict__ h_part, const float* __restrict__ b_fc,
                               float* __restrict__ out, int B) {
    int b = blockIdx.x * blockDim.x + threadIdx.x;
    if (b >= B) return;
    float v[NF];
    float m = -1e30f;
#pragma unroll
    for (int f = 0; f < NF; ++f) {
        float t = fmaxf(h_part[b * NF + f] + b_fc[f], 0.f);
        v[f] = t;
        m = fmaxf(m, t);
    }
    float s = 0.f;
#pragma unroll
    for (int f = 0; f < NF; ++f) { v[f] = expf(v[f] - m); s += v[f]; }
    float inv = 1.f / s;
#pragma unroll
    for (int f = 0; f < NF; ++f) out[b * NF + f] = v[f] * inv;
}

// ---------------- launch ----------------

extern "C" void kernel_launch(void* const* d_in, const int* in_sizes, int n_in,
                              void* d_out, int out_size, void* d_ws, size_t ws_size,
                              hipStream_t stream) {
    const float* x    = (const float*)d_in[0];
    const int*   rows = (const int*)d_in[1];
    const int*   cols = (const int*)d_in[2];
    const float* vals = (const float*)d_in[3];
    const float* W_gc = (const float*)d_in[4];
    const float* b_gc = (const float*)d_in[5];
    const float* W_fc = (const float*)d_in[6];
    const float* b_fc = (const float*)d_in[7];
    float* out = (float*)d_out;

    const int E = in_sizes[1];
    const int N = in_sizes[6] / (NF * NF);
    const int B = in_sizes[0] / N;

    // ---- workspace carve ----
    char* p = (char*)d_ws;
    int* counts    = (int*)p;   p += sizeof(int) * (size_t)N;
    int* row_start = (int*)p;   p += sizeof(int) * (size_t)(N + 1);
    int* cursor    = (int*)p;   p += sizeof(int) * (size_t)N;
    p = (char*)(((size_t)p + 15) & ~(size_t)15);
    u32* csr       = (u32*)p;   p += sizeof(u32) * (size_t)E;
    float* h_part  = (float*)p; p += sizeof(float) * (size_t)B * NF;
    p = (char*)(((size_t)p + 15) & ~(size_t)15);
    float* WgT     = (float*)p; p += sizeof(float) * (size_t)(NF * KCHEB);
    size_t fixed = (size_t)(p - (char*)d_ws);
    fixed = (fixed + 255) & ~(size_t)255;

    // X16[c][k][n][16] fp16 + C32[c][2][n][16] fp32, c in [0,8)
    __half* X16 = (__half*)((char*)d_ws + fixed);
    size_t x16b = ((size_t)NCH * KCHEB * N * 16 * sizeof(__half) + 255) & ~(size_t)255;
    float* C32 = (float*)((char*)d_ws + fixed + x16b);

    int BT = NCH * BCG;              // 128 batch per pass
    int nsc = B / BT;
    if (nsc < 1) nsc = 1;

    // ---- CSR build (once) + WgT prep ----
    {
        int H = B * NF;
        int cov = (N > H) ? N : H;
        init_kernel<<<(cov + 255) / 256, 256, 0, stream>>>(counts, h_part, W_gc, WgT, N, H);
        hist_kernel<<<(E + 255) / 256, 256, 0, stream>>>(rows, counts, E);
        scan_kernel<<<1, SCAN_THREADS, 0, stream>>>(counts, row_start, cursor, N);
        scatter_kernel<<<(E + 255) / 256, 256, 0, stream>>>(rows, cols, vals, cursor, csr, E);
    }

    int ntiles = (N + 63) / 64;
    int subs = (N + 127) / 128;
    int gridSpmm = 8 * subs;

    for (int c = 0; c < nsc; ++c) {
        int b0s = c * BT;
        transpose_kernel<<<ntiles, 256, 0, stream>>>(x, X16, C32, N, b0s);
        for (int k = 1; k < KCHEB; ++k) {
            float alpha = (k == 1) ? 1.f : 2.f;
            float beta  = (k == 1) ? 0.f : -1.f;
            spmm_kernel<<<gridSpmm, 256, 0, stream>>>(
                X16, C32, row_start, csr, N, k - 1, k, alpha, beta);
        }
        proj_fc_kernel<<<512, 1024, 0, stream>>>(X16, WgT, b_gc, W_fc, h_part, N, b0s);
    }

    softmax_kernel<<<1, 128, 0, stream>>>(h_part, b_fc, out, B);
}

// Round 7
// 1197.873 us; speedup vs baseline: 1.0548x; 1.0548x over previous
//
#include <hip/hip_runtime.h>
#include <hip/hip_bf16.h>
#include <hip/hip_fp16.h>
#include <math.h>

// Shapes: x [128,20000,1] f32; rows/cols [640000] i32; vals [640000] f32
// W_gc [20,10]; b_gc [10]; W_fc [200000,10]; b_fc [10]; out [128,10] f32.
//
// R20: L2-resident SpMM, clean experiment (R19 was confounded: scalar 4B
// nontemporal csr loads, 32B gathers, plane-major layout hurting proj).
//  - Keep R14 economy EXACTLY: [g][n][k][bb] layout, int2 8B csr entries,
//    multi-lane full-utilization gathers, same proj_fc/transpose structure.
//  - Change ONLY: BCG 64->32, G 2->4 (2 XCDs per chunk). Per-XCD L2 now
//    holds read plane (1.28MB) + write plane (1.28MB) = 2.56MB < 4MB.
//  - csr + carry accesses NONTEMPORAL so streams don't evict the planes.
//  - Theory: R14's 25us/step = LLC service (164MB/step @ 6.5TB/s) because
//    5.12MB working set + 5MB/step streams thrash the 4MB L2. If gathers
//    go L2-resident: ~9-14us/step. If not (>=22us), theory dead; revert.

#define NF 10
#define KCHEB 20
#define BCG 32                        // batch elems per chunk
#define COFF16 (KCHEB * BCG)          // 640 fp16 elems per node per chunk

typedef unsigned int u32;
typedef float v4f __attribute__((ext_vector_type(4)));
typedef u32 v2u __attribute__((ext_vector_type(2)));

// ---------------- CSR build + small prep ----------------

__global__ void init_kernel(int* counts, float* h_part, const float* __restrict__ W_gc,
                            float* __restrict__ WgT, int N, int H) {
    int i = blockIdx.x * blockDim.x + threadIdx.x;
    if (i < N) counts[i] = 0;
    if (i < H) h_part[i] = 0.f;
    if (i < KCHEB * NF) WgT[(i % NF) * KCHEB + (i / NF)] = W_gc[i];  // [j][k]
}

__global__ void hist_kernel(const int* __restrict__ rows, int* __restrict__ counts, int E) {
    int e = blockIdx.x * blockDim.x + threadIdx.x;
    if (e < E) atomicAdd(&counts[rows[e]], 1);
}

#define SCAN_THREADS 1024
__global__ void scan_kernel(const int* __restrict__ counts, int* __restrict__ row_start,
                            int* __restrict__ cursor, int N) {
    __shared__ int sh[SCAN_THREADS];
    int t = threadIdx.x;
    int CH = (N + SCAN_THREADS - 1) / SCAN_THREADS;
    int base = t * CH;
    int sum = 0;
    for (int i = 0; i < CH; ++i) {
        int idx = base + i;
        sum += (idx < N) ? counts[idx] : 0;
    }
    sh[t] = sum;
    __syncthreads();
    for (int off = 1; off < SCAN_THREADS; off <<= 1) {
        int v = (t >= off) ? sh[t - off] : 0;
        __syncthreads();
        sh[t] += v;
        __syncthreads();
    }
    int run = (t == 0) ? 0 : sh[t - 1];
    for (int i = 0; i < CH; ++i) {
        int idx = base + i;
        if (idx < N) {
            int v = counts[idx];
            row_start[idx] = run;
            cursor[idx] = run;
            run += v;
        }
    }
    if (t == SCAN_THREADS - 1) row_start[N] = run;
}

// csr[p] = (col*COFF16 [element offset of node's X16 row], bits(val))
__global__ void scatter_kernel(const int* __restrict__ rows, const int* __restrict__ cols,
                               const float* __restrict__ vals, int* __restrict__ cursor,
                               int2* __restrict__ csr, int E) {
    int e = blockIdx.x * blockDim.x + threadIdx.x;
    if (e >= E) return;
    int p = atomicAdd(&cursor[rows[e]], 1);
    csr[p] = make_int2(cols[e] * COFF16, __float_as_int(vals[e]));
}

// ---------------- T0 fill (tiled transpose; fp16 plane 0 + fp32 carry 0) ----

__global__ void transpose_kernel(const float* __restrict__ x, __half* __restrict__ X16,
                                 float* __restrict__ C32, int N, int ntiles, int b0s) {
    __shared__ float tile[BCG][65];
    int tid = threadIdx.x;
    int g = blockIdx.x / ntiles;
    int ti = blockIdx.x - g * ntiles;
    int n0 = ti * 64;
#pragma unroll
    for (int p = 0; p < 8; ++p) {
        int idx = p * 256 + tid;
        int row = idx >> 6;        // batch offset 0..31
        int col = idx & 63;        // node offset 0..63
        if (n0 + col < N)
            tile[row][col] = x[(size_t)(b0s + g * BCG + row) * N + n0 + col];
    }
    __syncthreads();
#pragma unroll
    for (int p = 0; p < 8; ++p) {
        int idx = p * 256 + tid;
        int nloc = idx >> 5;       // node offset 0..63
        int bb = idx & 31;         // batch offset 0..31
        int n = n0 + nloc;
        if (n < N) {
            float v = tile[bb][nloc];
            X16[(size_t)(g * N + n) * COFF16 + bb] = __float2half_rn(v);   // plane k=0
            C32[((size_t)(g * 2 + 0) * N + n) * BCG + bb] = v;             // carry slot 0
        }
    }
}

// ---------------- SpMM step ----------------
// Block = 256 thr = 32 rows x 8 bq lanes; each lane gathers 4 fp16 (8B), so a
// row's 8 lanes consume one 64B half-line per edge (full utilization).
// Chunk c = xcd>>1 (2 XCDs per chunk); planes L2-resident; csr+carry
// nontemporal so the streams don't evict the planes.

__global__ __launch_bounds__(256)
void spmm_kernel(__half* __restrict__ X16, float* __restrict__ C32,
                 const int* __restrict__ row_start, const int2* __restrict__ csr,
                 int N, int xpcShift, int subsPerChunk,
                 int kIn, int kOut, float alpha, float beta) {
    int xcd = blockIdx.x & 7;
    int chunk = xcd >> xpcShift;
    int xpcMask = (1 << xpcShift) - 1;
    int sub = (blockIdx.x >> 3) * (1 << xpcShift) + (xcd & xpcMask);
    if (sub >= subsPerChunk) return;
    int tid = threadIdx.x;
    int ln = tid >> 3;             // row 0..31
    int bq = tid & 7;              // 8 lanes x 4 fp16 = 32 batch
    int n = sub * 32 + ln;
    if (n >= N) return;
    int s = row_start[n];
    int e = row_start[n + 1];

    const __half* gin = X16 + (size_t)chunk * N * COFF16;
    int koff = kIn * BCG + bq * 4; // gather element offset within node row
    int bo = bq * 4;
    float acc[4];
#pragma unroll
    for (int q = 0; q < 4; ++q) acc[q] = 0.f;

    int i = s;
    for (; i + 4 <= e; i += 4) {
        v2u c0 = __builtin_nontemporal_load((const v2u*)(csr + i));
        v2u c1 = __builtin_nontemporal_load((const v2u*)(csr + i + 1));
        v2u c2 = __builtin_nontemporal_load((const v2u*)(csr + i + 2));
        v2u c3 = __builtin_nontemporal_load((const v2u*)(csr + i + 3));
        uint2 u0 = *(const uint2*)(gin + (int)c0.x + koff);
        uint2 u1 = *(const uint2*)(gin + (int)c1.x + koff);
        uint2 u2 = *(const uint2*)(gin + (int)c2.x + koff);
        uint2 u3 = *(const uint2*)(gin + (int)c3.x + koff);
        float v0 = __int_as_float((int)c0.y), v1 = __int_as_float((int)c1.y);
        float v2 = __int_as_float((int)c2.y), v3 = __int_as_float((int)c3.y);
        {
            float2 f0 = __half22float2(*(__half2*)&u0.x), f1 = __half22float2(*(__half2*)&u0.y);
            acc[0] += v0 * f0.x; acc[1] += v0 * f0.y; acc[2] += v0 * f1.x; acc[3] += v0 * f1.y;
        }
        {
            float2 f0 = __half22float2(*(__half2*)&u1.x), f1 = __half22float2(*(__half2*)&u1.y);
            acc[0] += v1 * f0.x; acc[1] += v1 * f0.y; acc[2] += v1 * f1.x; acc[3] += v1 * f1.y;
        }
        {
            float2 f0 = __half22float2(*(__half2*)&u2.x), f1 = __half22float2(*(__half2*)&u2.y);
            acc[0] += v2 * f0.x; acc[1] += v2 * f0.y; acc[2] += v2 * f1.x; acc[3] += v2 * f1.y;
        }
        {
            float2 f0 = __half22float2(*(__half2*)&u3.x), f1 = __half22float2(*(__half2*)&u3.y);
            acc[0] += v3 * f0.x; acc[1] += v3 * f0.y; acc[2] += v3 * f1.x; acc[3] += v3 * f1.y;
        }
    }
    for (; i < e; ++i) {
        v2u c0 = __builtin_nontemporal_load((const v2u*)(csr + i));
        uint2 u0 = *(const uint2*)(gin + (int)c0.x + koff);
        float v0 = __int_as_float((int)c0.y);
        float2 f0 = __half22float2(*(__half2*)&u0.x), f1 = __half22float2(*(__half2*)&u0.y);
        acc[0] += v0 * f0.x; acc[1] += v0 * f0.y; acc[2] += v0 * f1.x; acc[3] += v0 * f1.y;
    }

    // carry slot: (k-2)&1 == k&1 -> RMW same address (thread-private, safe)
    float* cslot = C32 + ((size_t)(chunk * 2 + (kOut & 1)) * N + n) * BCG + bo;
    float o[4];
#pragma unroll
    for (int q = 0; q < 4; ++q) o[q] = alpha * acc[q];
    if (beta != 0.f) {
        v4f pv = __builtin_nontemporal_load((const v4f*)cslot);
        o[0] += beta * pv.x; o[1] += beta * pv.y; o[2] += beta * pv.z; o[3] += beta * pv.w;
    }
    v4f sv = { o[0], o[1], o[2], o[3] };
    __builtin_nontemporal_store(sv, (v4f*)cslot);
    __half* o16 = X16 + (size_t)(chunk * N + n) * COFF16 + kOut * BCG + bo;
    uint2 h2;
    __half2 h01 = __floats2half2_rn(o[0], o[1]);
    __half2 h23 = __floats2half2_rn(o[2], o[3]);
    h2.x = *(u32*)&h01; h2.y = *(u32*)&h23;
    *(uint2*)o16 = h2;                     // normal store: next step reads it
}

// ---------------- Fused projection + FC partial ----------------
// 1024 thr = 16 waves. Wave = one node; lanes = 2 chunks x 32 bb; wv&1
// selects chunk pair (g0=0/2). Weights wave-uniform -> scalar loads.

__global__ __launch_bounds__(1024, 8)
void proj_fc_kernel(const __half* __restrict__ X16,
                    const float* __restrict__ WgT,    // [j][k] = [10][20]
                    const float* __restrict__ b_gc,
                    const float* __restrict__ W_fc,
                    float* __restrict__ h_part,
                    int N, int b0s) {
    __shared__ float sRed[128 * 11];
    int tid = threadIdx.x;
    for (int i = tid; i < 128 * 11; i += 1024) sRed[i] = 0.f;
    __syncthreads();

    int lane = tid & 63;
    int bb = lane & (BCG - 1);                           // 0..31
    int lg = lane >> 5;                                  // 0..1
    int wv = __builtin_amdgcn_readfirstlane(tid >> 6);   // wave 0..15, uniform
    int nslot = wv >> 1;                                 // 0..7
    int g0 = (wv & 1) * 2;
    int g = g0 + lg;                                     // chunk 0..3
    int b = g * BCG + bb;                                // batch 0..127

    float h_loc[NF];
#pragma unroll
    for (int f = 0; f < NF; ++f) h_loc[f] = 0.f;

    int ngroups = (N + 7) / 8;
    for (int grp = blockIdx.x; grp < ngroups; grp += gridDim.x) {
        int n = grp * 8 + nslot;                         // uniform per wave
        if (n < N) {
            float xt[KCHEB];
            const __half* xp = X16 + (size_t)(g * N + n) * COFF16 + bb;
#pragma unroll
            for (int k = 0; k < KCHEB; ++k) xt[k] = __half2float(xp[k * BCG]);

            const float* wfBase = W_fc + (size_t)n * (NF * NF);
#pragma unroll 1
            for (int j = 0; j < NF; ++j) {
                const float* wg = WgT + j * KCHEB;       // contiguous 20f
                float gc = b_gc[j];
#pragma unroll
                for (int k = 0; k < KCHEB; ++k) gc += wg[k] * xt[k];
                gc = fmaxf(gc, 0.f);
                const float* wf = wfBase + j * NF;       // contiguous 10f
#pragma unroll
                for (int f = 0; f < NF; ++f) h_loc[f] += gc * wf[f];
            }
        }
    }
#pragma unroll
    for (int f = 0; f < NF; ++f) atomicAdd(&sRed[b * 11 + f], h_loc[f]);
    __syncthreads();
    for (int i = tid; i < 128 * NF; i += 1024) {
        int rb = i / NF;
        int rf = i - rb * NF;
        atomicAdd(&h_part[(size_t)(b0s + rb) * NF + rf], sRed[rb * 11 + rf]);
    }
}

// ---------------- Bias + ReLU + softmax ----------------

__global__ void softmax_kernel(const float* __restrict__ h_part, const float* __restrict__ b_fc,
                               float* __restrict__ out, int B) {
    int b = blockIdx.x * blockDim.x + threadIdx.x;
    if (b >= B) return;
    float v[NF];
    float m = -1e30f;
#pragma unroll
    for (int f = 0; f < NF; ++f) {
        float t = fmaxf(h_part[b * NF + f] + b_fc[f], 0.f);
        v[f] = t;
        m = fmaxf(m, t);
    }
    float s = 0.f;
#pragma unroll
    for (int f = 0; f < NF; ++f) { v[f] = expf(v[f] - m); s += v[f]; }
    float inv = 1.f / s;
#pragma unroll
    for (int f = 0; f < NF; ++f) out[b * NF + f] = v[f] * inv;
}

// ---------------- launch ----------------

static inline int ilog2i(int v) { int s = 0; while ((1 << s) < v) ++s; return s; }

extern "C" void kernel_launch(void* const* d_in, const int* in_sizes, int n_in,
                              void* d_out, int out_size, void* d_ws, size_t ws_size,
                              hipStream_t stream) {
    const float* x    = (const float*)d_in[0];
    const int*   rows = (const int*)d_in[1];
    const int*   cols = (const int*)d_in[2];
    const float* vals = (const float*)d_in[3];
    const float* W_gc = (const float*)d_in[4];
    const float* b_gc = (const float*)d_in[5];
    const float* W_fc = (const float*)d_in[6];
    const float* b_fc = (const float*)d_in[7];
    float* out = (float*)d_out;

    const int E = in_sizes[1];
    const int N = in_sizes[6] / (NF * NF);
    const int B = in_sizes[0] / N;

    // ---- workspace carve ----
    char* p = (char*)d_ws;
    int* counts    = (int*)p;   p += sizeof(int) * (size_t)N;
    int* row_start = (int*)p;   p += sizeof(int) * (size_t)(N + 1);
    int* cursor    = (int*)p;   p += sizeof(int) * (size_t)N;
    p = (char*)(((size_t)p + 15) & ~(size_t)15);
    int2* csr      = (int2*)p;  p += sizeof(int2) * (size_t)E;
    float* h_part  = (float*)p; p += sizeof(float) * (size_t)B * NF;
    p = (char*)(((size_t)p + 15) & ~(size_t)15);
    float* WgT     = (float*)p; p += sizeof(float) * (size_t)(NF * KCHEB);
    size_t fixed = (size_t)(p - (char*)d_ws);
    fixed = (fixed + 255) & ~(size_t)255;

    // 4 chunks of BCG=32 resident; B=128 -> single pass
    size_t perChunk16 = (size_t)N * COFF16 * sizeof(__half);     // 25.6 MB
    size_t perCarry   = (size_t)2 * N * BCG * sizeof(float);     // 5.12 MB
    int G = (B >= 4 * BCG) ? 4 : ((B >= 2 * BCG) ? 2 : 1);
    while (G > 1 && fixed + (size_t)G * (perChunk16 + perCarry) > ws_size) G >>= 1;
    __half* X16 = (__half*)((char*)d_ws + fixed);
    size_t x16b = ((size_t)G * perChunk16 + 255) & ~(size_t)255;
    float* C32 = (float*)((char*)d_ws + fixed + x16b);
    int xpcShift = 3 - ilog2i(G);     // G=4 -> 1 (2 XCDs/chunk)
    int BT = G * BCG;
    int nsc = B / BT;
    if (nsc < 1) nsc = 1;

    // ---- CSR build + WgT prep ----
    {
        int H = B * NF;
        int cov = (N > H) ? N : H;
        init_kernel<<<(cov + 255) / 256, 256, 0, stream>>>(counts, h_part, W_gc, WgT, N, H);
        hist_kernel<<<(E + 255) / 256, 256, 0, stream>>>(rows, counts, E);
        scan_kernel<<<1, SCAN_THREADS, 0, stream>>>(counts, row_start, cursor, N);
        scatter_kernel<<<(E + 255) / 256, 256, 0, stream>>>(rows, cols, vals, cursor, csr, E);
    }

    int ntiles = (N + 63) / 64;
    int subsPerChunk = (N + 31) / 32;
    int xpc = 1 << xpcShift;
    int gridSpmm = 8 * ((subsPerChunk + xpc - 1) / xpc);

    for (int c = 0; c < nsc; ++c) {
        int b0s = c * BT;
        transpose_kernel<<<G * ntiles, 256, 0, stream>>>(x, X16, C32, N, ntiles, b0s);
        for (int k = 1; k < KCHEB; ++k) {
            float alpha = (k == 1) ? 1.f : 2.f;
            float beta  = (k == 1) ? 0.f : -1.f;
            spmm_kernel<<<gridSpmm, 256, 0, stream>>>(
                X16, C32, row_start, csr, N, xpcShift, subsPerChunk,
                k - 1, k, alpha, beta);
        }
        proj_fc_kernel<<<512, 1024, 0, stream>>>(X16, WgT, b_gc, W_fc, h_part, N, b0s);
    }

    softmax_kernel<<<1, 128, 0, stream>>>(h_part, b_fc, out, B);
}

// Round 8
// 561.901 us; speedup vs baseline: 2.2487x; 2.1318x over previous
//
#include <hip/hip_runtime.h>
#include <hip/hip_bf16.h>
#include <hip/hip_fp16.h>
#include <math.h>

// Shapes: x [128,20000,1] f32; rows/cols [640000] i32; vals [640000] f32
// W_gc [20,10]; b_gc [10]; W_fc [200000,10]; b_fc [10]; out [128,10] f32.
//
// R21 = R17 (best verified, 597us) + parallel CSR scan.
//  - SpMM floor is structural: dispatch-boundary L2 writeback/invalidate
//    (needed for cross-XCD coherence) makes every step start L2-cold, so
//    the 32x column reuse is only captured by LLC. 164MB payload/step @
//    ~6.5TB/s LLC line service = 25us/step. Payload already minimal
//    (BCG=64 -> one 128B line per edge-gather). Verified by falsification:
//    gather/reduce split 33us (R18b), plane-major 65us (R19), small-chunk
//    L2-fit 55us (R20) -- all worse.
//  - proj_fc: R17 wave-uniform scalar-weight structure, 56us (latency
//    plateau at 100% static occupancy).
//  - NEW: old single-block scan_kernel was ~50us (serial CH=20 + 0.14%
//    occupancy, seen directly as 100us at 2N rows in R18b). Replaced with
//    3-phase multi-block scan (~8us): block-wise Hillis-Steele -> tiny
//    block-sum scan -> add offsets.

#define NF 10
#define KCHEB 20
#define BCG 64                        // batch elems per chunk
#define COFF16 (KCHEB * BCG)          // 1280 fp16 elems per node in X16

typedef unsigned int u32;

// ---------------- CSR build + small prep ----------------

__global__ void init_kernel(int* counts, float* h_part, const float* __restrict__ W_gc,
                            float* __restrict__ WgT, int N, int H) {
    int i = blockIdx.x * blockDim.x + threadIdx.x;
    if (i < N) counts[i] = 0;
    if (i < H) h_part[i] = 0.f;
    if (i < KCHEB * NF) WgT[(i % NF) * KCHEB + (i / NF)] = W_gc[i];  // [j][k]
}

__global__ void hist_kernel(const int* __restrict__ rows, int* __restrict__ counts, int E) {
    int e = blockIdx.x * blockDim.x + threadIdx.x;
    if (e < E) atomicAdd(&counts[rows[e]], 1);
}

// ---- 3-phase scan: ex[i] = exclusive prefix within block; bsum = block sums
#define SB 1024
__global__ void scan1_kernel(const int* __restrict__ counts, int* __restrict__ ex,
                             int* __restrict__ bsum, int N) {
    __shared__ int sh[SB];
    int t = threadIdx.x;
    int i = blockIdx.x * SB + t;
    int v = (i < N) ? counts[i] : 0;
    sh[t] = v;
    __syncthreads();
    for (int off = 1; off < SB; off <<= 1) {
        int u = (t >= off) ? sh[t - off] : 0;
        __syncthreads();
        sh[t] += u;
        __syncthreads();
    }
    if (i < N) ex[i] = sh[t] - v;
    if (t == SB - 1) bsum[blockIdx.x] = sh[t];
}

__global__ void scan2_kernel(const int* __restrict__ bsum, int* __restrict__ boff, int nb) {
    if (threadIdx.x == 0) {
        int run = 0;
        for (int i = 0; i < nb; ++i) { boff[i] = run; run += bsum[i]; }
        boff[nb] = run;
    }
}

__global__ void scan3_kernel(int* __restrict__ row_start, int* __restrict__ cursor,
                             const int* __restrict__ ex, const int* __restrict__ boff,
                             int N, int nb) {
    int i = blockIdx.x * blockDim.x + threadIdx.x;
    if (i < N) {
        int v = ex[i] + boff[i >> 10];
        row_start[i] = v;
        cursor[i] = v;
    }
    if (i == N) row_start[N] = boff[nb];
}

// csr[p] = (col*COFF16 [element offset of node's X16 row], bits(val))
__global__ void scatter_kernel(const int* __restrict__ rows, const int* __restrict__ cols,
                               const float* __restrict__ vals, int* __restrict__ cursor,
                               int2* __restrict__ csr, int E) {
    int e = blockIdx.x * blockDim.x + threadIdx.x;
    if (e >= E) return;
    int p = atomicAdd(&cursor[rows[e]], 1);
    csr[p] = make_int2(cols[e] * COFF16, __float_as_int(vals[e]));
}

// ---------------- T0 fill (tiled transpose; fp16 plane 0 + fp32 carry 0) ----

__global__ void transpose_kernel(const float* __restrict__ x, __half* __restrict__ X16,
                                 float* __restrict__ C32, int N, int ntiles, int b0s) {
    __shared__ float tile[BCG][65];
    int tid = threadIdx.x;
    int g = blockIdx.x / ntiles;
    int ti = blockIdx.x - g * ntiles;
    int n0 = ti * 64;
#pragma unroll
    for (int p = 0; p < 16; ++p) {
        int idx = p * 256 + tid;
        int row = idx >> 6;        // batch offset 0..63
        int col = idx & 63;        // node offset 0..63
        if (n0 + col < N)
            tile[row][col] = x[(size_t)(b0s + g * BCG + row) * N + n0 + col];
    }
    __syncthreads();
#pragma unroll
    for (int p = 0; p < 16; ++p) {
        int idx = p * 256 + tid;
        int nloc = idx >> 6;       // node offset 0..63
        int bb = idx & 63;         // batch offset 0..63
        int n = n0 + nloc;
        if (n < N) {
            float v = tile[bb][nloc];
            X16[(size_t)(g * N + n) * COFF16 + bb] = __float2half_rn(v);   // plane k=0
            C32[((size_t)(g * 2 + 0) * N + n) * BCG + bb] = v;             // carry slot 0
        }
    }
}

// ---------------- SpMM step ----------------
// Block = 256 thr = 32 rows x 8 bq lanes; each lane gathers 8 fp16 (16B), so a
// row's 8 lanes consume exactly one 128B line per edge.
// Carry math fp32 via C32 rotating slots; outputs: C32[k&1] + X16 plane k.

__global__ __launch_bounds__(256)
void spmm_kernel(__half* __restrict__ X16, float* __restrict__ C32,
                 const int* __restrict__ row_start, const int2* __restrict__ csr,
                 int N, int xpcShift, int subsPerChunk,
                 int kIn, int kOut, float alpha, float beta) {
    int xcd = blockIdx.x & 7;
    int chunk = xcd >> xpcShift;
    int xpcMask = (1 << xpcShift) - 1;
    int sub = (blockIdx.x >> 3) * (1 << xpcShift) + (xcd & xpcMask);
    if (sub >= subsPerChunk) return;
    int tid = threadIdx.x;
    int ln = tid >> 3;             // row 0..31
    int bq = tid & 7;              // 8 lanes x 8 fp16 = 64 batch
    int n = sub * 32 + ln;
    if (n >= N) return;
    int s = row_start[n];
    int e = row_start[n + 1];

    const __half* gin = X16 + (size_t)chunk * N * COFF16;
    int koff = kIn * BCG + bq * 8; // gather element offset within node row
    int bo = bq * 8;
    float acc[8];
#pragma unroll
    for (int q = 0; q < 8; ++q) acc[q] = 0.f;

    int i = s;
    for (; i + 4 <= e; i += 4) {
        int2 p0 = csr[i], p1 = csr[i + 1], p2 = csr[i + 2], p3 = csr[i + 3];
        uint4 u0 = *(const uint4*)(gin + p0.x + koff);
        uint4 u1 = *(const uint4*)(gin + p1.x + koff);
        uint4 u2 = *(const uint4*)(gin + p2.x + koff);
        uint4 u3 = *(const uint4*)(gin + p3.x + koff);
        float v0 = __int_as_float(p0.y), v1 = __int_as_float(p1.y);
        float v2 = __int_as_float(p2.y), v3 = __int_as_float(p3.y);
        {
            float2 f0 = __half22float2(*(__half2*)&u0.x), f1 = __half22float2(*(__half2*)&u0.y);
            float2 f2 = __half22float2(*(__half2*)&u0.z), f3 = __half22float2(*(__half2*)&u0.w);
            acc[0] += v0 * f0.x; acc[1] += v0 * f0.y; acc[2] += v0 * f1.x; acc[3] += v0 * f1.y;
            acc[4] += v0 * f2.x; acc[5] += v0 * f2.y; acc[6] += v0 * f3.x; acc[7] += v0 * f3.y;
        }
        {
            float2 f0 = __half22float2(*(__half2*)&u1.x), f1 = __half22float2(*(__half2*)&u1.y);
            float2 f2 = __half22float2(*(__half2*)&u1.z), f3 = __half22float2(*(__half2*)&u1.w);
            acc[0] += v1 * f0.x; acc[1] += v1 * f0.y; acc[2] += v1 * f1.x; acc[3] += v1 * f1.y;
            acc[4] += v1 * f2.x; acc[5] += v1 * f2.y; acc[6] += v1 * f3.x; acc[7] += v1 * f3.y;
        }
        {
            float2 f0 = __half22float2(*(__half2*)&u2.x), f1 = __half22float2(*(__half2*)&u2.y);
            float2 f2 = __half22float2(*(__half2*)&u2.z), f3 = __half22float2(*(__half2*)&u2.w);
            acc[0] += v2 * f0.x; acc[1] += v2 * f0.y; acc[2] += v2 * f1.x; acc[3] += v2 * f1.y;
            acc[4] += v2 * f2.x; acc[5] += v2 * f2.y; acc[6] += v2 * f3.x; acc[7] += v2 * f3.y;
        }
        {
            float2 f0 = __half22float2(*(__half2*)&u3.x), f1 = __half22float2(*(__half2*)&u3.y);
            float2 f2 = __half22float2(*(__half2*)&u3.z), f3 = __half22float2(*(__half2*)&u3.w);
            acc[0] += v3 * f0.x; acc[1] += v3 * f0.y; acc[2] += v3 * f1.x; acc[3] += v3 * f1.y;
            acc[4] += v3 * f2.x; acc[5] += v3 * f2.y; acc[6] += v3 * f3.x; acc[7] += v3 * f3.y;
        }
    }
    for (; i < e; ++i) {
        int2 p0 = csr[i];
        uint4 u0 = *(const uint4*)(gin + p0.x + koff);
        float v0 = __int_as_float(p0.y);
        float2 f0 = __half22float2(*(__half2*)&u0.x), f1 = __half22float2(*(__half2*)&u0.y);
        float2 f2 = __half22float2(*(__half2*)&u0.z), f3 = __half22float2(*(__half2*)&u0.w);
        acc[0] += v0 * f0.x; acc[1] += v0 * f0.y; acc[2] += v0 * f1.x; acc[3] += v0 * f1.y;
        acc[4] += v0 * f2.x; acc[5] += v0 * f2.y; acc[6] += v0 * f3.x; acc[7] += v0 * f3.y;
    }

    // carry slot: (k-2)&1 == k&1, so read T_{k-2} and write T_k at the SAME
    // address (thread-private location -> safe).
    float* cslot = C32 + ((size_t)(chunk * 2 + (kOut & 1)) * N + n) * BCG + bo;
    float o[8];
#pragma unroll
    for (int q = 0; q < 8; ++q) o[q] = alpha * acc[q];
    if (beta != 0.f) {
        const float4 pv0 = *(const float4*)(cslot);
        const float4 pv1 = *(const float4*)(cslot + 4);
        o[0] += beta * pv0.x; o[1] += beta * pv0.y; o[2] += beta * pv0.z; o[3] += beta * pv0.w;
        o[4] += beta * pv1.x; o[5] += beta * pv1.y; o[6] += beta * pv1.z; o[7] += beta * pv1.w;
    }
    *(float4*)(cslot)     = make_float4(o[0], o[1], o[2], o[3]);
    *(float4*)(cslot + 4) = make_float4(o[4], o[5], o[6], o[7]);
    __half* o16 = X16 + (size_t)(chunk * N + n) * COFF16 + kOut * BCG + bo;
    uint4 h4;
    __half2 h01 = __floats2half2_rn(o[0], o[1]);
    __half2 h23 = __floats2half2_rn(o[2], o[3]);
    __half2 h45 = __floats2half2_rn(o[4], o[5]);
    __half2 h67 = __floats2half2_rn(o[6], o[7]);
    h4.x = *(u32*)&h01; h4.y = *(u32*)&h23; h4.z = *(u32*)&h45; h4.w = *(u32*)&h67;
    *(uint4*)o16 = h4;
}

// ---------------- Fused projection + FC partial ----------------
// Block = 1024 thr = 16 waves; wave = one node x 64 bb lanes. All weight reads
// (WgT row, W_fc row, bias) are wave-uniform -> scalar loads on the SMEM pipe.
// Grid 256*G -> 2 blocks/CU = 32 waves/CU (100% static occupancy; VGPR=24
// leaves registers unconstrained). Zero LDS in hot loop.
// j-loop rolled so LICM can't hoist 200 s_loads (SGPR spill hazard).

__global__ __launch_bounds__(1024, 8)
void proj_fc_kernel(const __half* __restrict__ X16,
                    const float* __restrict__ WgT,    // [j][k] = [10][20]
                    const float* __restrict__ b_gc,
                    const float* __restrict__ W_fc,
                    float* __restrict__ h_part,
                    int N, int b0s, int G) {
    __shared__ float sRed[BCG * 11];
    int tid = threadIdx.x;
    for (int i = tid; i < BCG * 11; i += 1024) sRed[i] = 0.f;
    __syncthreads();

    int g = blockIdx.x % G;
    int bidx = blockIdx.x / G;
    int nblk = gridDim.x / G;

    int bb = tid & (BCG - 1);
    int wv = __builtin_amdgcn_readfirstlane(tid >> 6);   // wave slot 0..15, uniform

    float h_loc[NF];
#pragma unroll
    for (int f = 0; f < NF; ++f) h_loc[f] = 0.f;

    const __half* chunkBase = X16 + (size_t)g * N * COFF16;
    int ngroups = (N + 15) / 16;
    for (int grp = bidx; grp < ngroups; grp += nblk) {
        int n = grp * 16 + wv;                           // uniform per wave
        if (n < N) {
            float xt[KCHEB];
            const __half* xp = chunkBase + (size_t)n * COFF16 + bb;
#pragma unroll
            for (int k = 0; k < KCHEB; ++k) xt[k] = __half2float(xp[k * BCG]);

            const float* wfBase = W_fc + (size_t)n * (NF * NF);
#pragma unroll 1
            for (int j = 0; j < NF; ++j) {
                const float* wg = WgT + j * KCHEB;       // 16B-aligned, contiguous 20f
                float gc = b_gc[j];
#pragma unroll
                for (int k = 0; k < KCHEB; ++k) gc += wg[k] * xt[k];
                gc = fmaxf(gc, 0.f);
                const float* wf = wfBase + j * NF;       // 8B-aligned, contiguous 10f
#pragma unroll
                for (int f = 0; f < NF; ++f) h_loc[f] += gc * wf[f];
            }
        }
    }
#pragma unroll
    for (int f = 0; f < NF; ++f) atomicAdd(&sRed[bb * 11 + f], h_loc[f]);
    __syncthreads();
    for (int i = tid; i < BCG * NF; i += 1024) {
        int rb = i / NF;
        int rf = i - rb * NF;
        atomicAdd(&h_part[(size_t)(b0s + g * BCG + rb) * NF + rf], sRed[rb * 11 + rf]);
    }
}

// ---------------- Bias + ReLU + softmax ----------------

__global__ void softmax_kernel(const float* __restrict__ h_part, const float* __restrict__ b_fc,
                               float* __restrict__ out, int B) {
    int b = blockIdx.x * blockDim.x + threadIdx.x;
    if (b >= B) return;
    float v[NF];
    float m = -1e30f;
#pragma unroll
    for (int f = 0; f < NF; ++f) {
        float t = fmaxf(h_part[b * NF + f] + b_fc[f], 0.f);
        v[f] = t;
        m = fmaxf(m, t);
    }
    float s = 0.f;
#pragma unroll
    for (int f = 0; f < NF; ++f) { v[f] = expf(v[f] - m); s += v[f]; }
    float inv = 1.f / s;
#pragma unroll
    for (int f = 0; f < NF; ++f) out[b * NF + f] = v[f] * inv;
}

// ---------------- launch ----------------

extern "C" void kernel_launch(void* const* d_in, const int* in_sizes, int n_in,
                              void* d_out, int out_size, void* d_ws, size_t ws_size,
                              hipStream_t stream) {
    const float* x    = (const float*)d_in[0];
    const int*   rows = (const int*)d_in[1];
    const int*   cols = (const int*)d_in[2];
    const float* vals = (const float*)d_in[3];
    const float* W_gc = (const float*)d_in[4];
    const float* b_gc = (const float*)d_in[5];
    const float* W_fc = (const float*)d_in[6];
    const float* b_fc = (const float*)d_in[7];
    float* out = (float*)d_out;

    const int E = in_sizes[1];
    const int N = in_sizes[6] / (NF * NF);
    const int B = in_sizes[0] / N;

    // ---- workspace carve ----
    char* p = (char*)d_ws;
    int* counts    = (int*)p;   p += sizeof(int) * (size_t)N;
    int* row_start = (int*)p;   p += sizeof(int) * (size_t)(N + 1);
    int* cursor    = (int*)p;   p += sizeof(int) * (size_t)N;
    int* exbuf     = (int*)p;   p += sizeof(int) * (size_t)N;
    int* bsum      = (int*)p;   p += sizeof(int) * 64;
    int* boff      = (int*)p;   p += sizeof(int) * 64;
    p = (char*)(((size_t)p + 15) & ~(size_t)15);
    int2* csr      = (int2*)p;  p += sizeof(int2) * (size_t)E;
    float* h_part  = (float*)p; p += sizeof(float) * (size_t)B * NF;
    p = (char*)(((size_t)p + 15) & ~(size_t)15);
    float* WgT     = (float*)p; p += sizeof(float) * (size_t)(NF * KCHEB);
    size_t fixed = (size_t)(p - (char*)d_ws);
    fixed = (fixed + 255) & ~(size_t)255;

    // G chunks of BCG=64 resident (G in {2,1}); B=128 -> G=2, single pass
    size_t perChunk16 = (size_t)N * COFF16 * sizeof(__half);     // 51.2 MB
    size_t perCarry   = (size_t)2 * N * BCG * sizeof(float);     // 10.24 MB
    int G = (B >= 2 * BCG) ? 2 : 1;
    while (G > 1 && fixed + (size_t)G * (perChunk16 + perCarry) > ws_size) G >>= 1;
    __half* X16 = (__half*)((char*)d_ws + fixed);
    size_t x16b = ((size_t)G * perChunk16 + 255) & ~(size_t)255;
    float* C32 = (float*)((char*)d_ws + fixed + x16b);
    int xpcShift = (G == 2) ? 2 : 3;
    int BT = G * BCG;
    int nsc = B / BT;

    // ---- CSR build (parallel scan) + WgT prep ----
    {
        int H = B * NF;
        int cov = (N > H) ? N : H;
        int nb = (N + SB - 1) / SB;
        init_kernel<<<(cov + 255) / 256, 256, 0, stream>>>(counts, h_part, W_gc, WgT, N, H);
        hist_kernel<<<(E + 255) / 256, 256, 0, stream>>>(rows, counts, E);
        scan1_kernel<<<nb, SB, 0, stream>>>(counts, exbuf, bsum, N);
        scan2_kernel<<<1, 64, 0, stream>>>(bsum, boff, nb);
        scan3_kernel<<<(N + 256) / 256, 256, 0, stream>>>(row_start, cursor, exbuf, boff, N, nb);
        scatter_kernel<<<(E + 255) / 256, 256, 0, stream>>>(rows, cols, vals, cursor, csr, E);
    }

    int ntiles = (N + 63) / 64;
    int subsPerChunk = (N + 31) / 32;
    int xpc = 1 << xpcShift;
    int gridSpmm = 8 * ((subsPerChunk + xpc - 1) / xpc);

    for (int c = 0; c < nsc; ++c) {
        int b0s = c * BT;
        transpose_kernel<<<G * ntiles, 256, 0, stream>>>(x, X16, C32, N, ntiles, b0s);
        for (int k = 1; k < KCHEB; ++k) {
            float alpha = (k == 1) ? 1.f : 2.f;
            float beta  = (k == 1) ? 0.f : -1.f;
            spmm_kernel<<<gridSpmm, 256, 0, stream>>>(
                X16, C32, row_start, csr, N, xpcShift, subsPerChunk,
                k - 1, k, alpha, beta);
        }
        proj_fc_kernel<<<256 * G, 1024, 0, stream>>>(X16, WgT, b_gc, W_fc, h_part, N, b0s, G);
    }

    softmax_kernel<<<1, 128, 0, stream>>>(h_part, b_fc, out, B);
}